// Round 13
// baseline (149.492 us; speedup 1.0000x reference)
//
#include <hip/hip_runtime.h>
#include <hip/hip_bf16.h>

typedef __hip_bfloat16 bf16;
typedef __attribute__((ext_vector_type(8))) short short8v;   // 8 bf16 (4 VGPRs)
typedef __attribute__((ext_vector_type(4))) float f32x4;

constexpr int NB  = 32;
constexpr int NM  = 256;
constexpr int DD  = 256;
constexpr int NH  = 8;
constexpr int QP  = 64;
constexpr int FF  = 32;
constexpr int NT  = NB * NM;        // 8192
constexpr int HD2 = NT * DD;        // 2097152
constexpr float QSCALE = 0.17677669529663687f;

__device__ __forceinline__ float b2f(unsigned short u) {
  return __uint_as_float(((unsigned)u) << 16);
}
__device__ __forceinline__ short f2b(float f) {
  union { bf16 h; short s; } u;
  u.h = __float2bfloat16(f);
  return u.s;
}

__device__ __forceinline__ void bn_coeffs(const float* bnstat, const float* gamma,
                                          const float* beta, float* bnsc, float* bnsh,
                                          int t) {
  if (t < 256) {
    float sc = 1.f, sh = 0.f;
    if (bnstat) {
      const float mean = bnstat[t] * (1.0f / NT);
      const float var = bnstat[256 + t] * (1.0f / NT) - mean * mean;
      const float rstd = rsqrtf(var + 1e-5f);
      sc = rstd * gamma[t];
      sh = beta[t] - mean * sc;
    }
    bnsc[t] = sc; bnsh[t] = sh;
  }
}

// ---------------------------------------------------------------- setup: z copy/zbf, bna, phi, Wt
__global__ __launch_bounds__(256) void k_setup(const float* __restrict__ z,
                                               float* __restrict__ outz,
                                               short* __restrict__ zbf,
                                               float* __restrict__ bna,
                                               const float* __restrict__ Lam,
                                               const float* __restrict__ pW1,
                                               const float* __restrict__ pb1,
                                               const float* __restrict__ pW2,
                                               const float* __restrict__ pb2,
                                               float* __restrict__ phiA,
                                               const float* __restrict__ Wq,
                                               const float* __restrict__ Wk,
                                               const float* __restrict__ Wv,
                                               const float* __restrict__ Wo,
                                               short* __restrict__ Wt) {
  __shared__ float Ts[32][33];
  const int t = threadIdx.x;
  const int idx = blockIdx.x * 256 + t;                   // 262144 float4s of z
  {
    const float4 v = ((const float4*)z)[idx];
    ((float4*)outz)[idx] = v;
    short4 s;
    s.x = f2b(v.x); s.y = f2b(v.y); s.z = f2b(v.z); s.w = f2b(v.w);
    ((short4*)zbf)[idx] = s;
  }
  if (idx < 4 * 512) bna[idx] = 0.f;
  if (idx < 4 * 2048) {                                   // phi MLP, all layers
    const int l = idx >> 11;
    const int t2 = idx & 2047;
    const int b = t2 >> 6, qp = t2 & 63;
    const float lam = Lam[b * QP + qp];
    const float* w1 = pW1 + l * FF;
    const float* bb1 = pb1 + l * FF;
    const float* w2 = pW2 + l * FF * NH;
    const float* bb2 = pb2 + l * NH;
    float acc[NH];
#pragma unroll
    for (int h = 0; h < NH; ++h) acc[h] = bb2[h];
    for (int f = 0; f < FF; ++f) {
      float a = lam * w1[f] + bb1[f];
      a = a > 0.f ? a : 0.f;
#pragma unroll
      for (int h = 0; h < NH; ++h) acc[h] += a * w2[f * NH + h];
    }
#pragma unroll
    for (int h = 0; h < NH; ++h)
      phiA[(((size_t)l * NB + b) * NH + h) * QP + qp] = acc[h];
  }
  if (blockIdx.x < 128) {                                 // Wt transpose
    const int mat = blockIdx.x >> 3;                      // 16 matrices
    const int l = mat >> 2, wsel = mat & 3;
    const float* W = (wsel == 0 ? Wq : wsel == 1 ? Wk : wsel == 2 ? Wv : Wo) + l * DD * DD;
    const int j0 = (blockIdx.x & 7) * 32;
    short* outw = Wt + (size_t)mat * DD * DD;
    const int jj = t & 31, kk8 = t >> 5;
    for (int k0 = 0; k0 < DD; k0 += 32) {
      __syncthreads();
#pragma unroll
      for (int s = 0; s < 4; ++s) {
        const int kl = s * 8 + kk8;
        Ts[kl][jj] = W[(k0 + kl) * DD + j0 + jj];
      }
      __syncthreads();
#pragma unroll
      for (int s = 0; s < 4; ++s) {
        const int jl = (t >> 5) + s * 8;
        const int kl = t & 31;
        outw[(size_t)(j0 + jl) * DD + k0 + kl] = f2b(Ts[kl][jl]);
      }
    }
  }
}

// ---------------------------------------------------------------- fused qkv-proj + bias + attention
// One block per (b,h) (XCD swizzle), 512 threads = 8 waves.
// Phase A: H direct-to-register (per-wave-exclusive rows), Ws staged once in LDS.
// Phase B: S = Q'K'^T with Q'=[q*scale, z], K'=[k, phi.z]; softmax; PV.
__global__ __launch_bounds__(512, 2) void k_fat(const float* __restrict__ hsrc,
                                                const short* __restrict__ WtL,   // layer base (4 mats)
                                                const float* __restrict__ bnstat,
                                                const float* __restrict__ gamma,
                                                const float* __restrict__ beta,
                                                const float* __restrict__ bq_l,
                                                const float* __restrict__ bk_l,
                                                const float* __restrict__ bv_l,
                                                const short* __restrict__ zbf,
                                                const float* __restrict__ phiAll,
                                                short* __restrict__ obf, int l) {
  // LDS map (159232 B total):
  //  [0, 98304)        Ks: K'[256 rows][384B pitch]
  //  [65536, 114688)   Ws (phase A only): 96 rows x 512B -- overlays Ks tail + Vt;
  //                    all Ks/Vt writes happen after the post-phase-A barrier.
  //  [98304, 114688)   Vt: V^T[32][512B]
  //  [114688, 155648)  Pw: 8 waves x 5120B (qtmp 2560 + PV double-buffer)
  //  [155648, 156672)  rs_l (256 f32)
  //  [156672, 157184)  ph2 (128 f32)
  //  [157184, 159232)  bnsc/bnsh (256+256 f32)
  __shared__ __align__(16) char SM[159232];
  char* Ks = SM;
  char* Ws = SM + 65536;              // phase A alias (48KB)
  char* Vt = SM + 98304;
  char* Pw = SM + 114688;
  float* rs_l = (float*)(SM + 155648);
  float* ph2  = (float*)(SM + 156672);
  float* bnsc = (float*)(SM + 157184);
  float* bnsh = bnsc + 256;

  const int t = threadIdx.x;
  const int bh = (blockIdx.x & 7) * 32 + (blockIdx.x >> 3);   // XCD swizzle
  const int b = bh >> 3, hh = bh & 7;
  const int bnode = b * 256;

  bn_coeffs(bnstat, gamma, beta, bnsc, bnsh, t);
  if (t < 128)
    ph2[t] = phiAll[(((size_t)l * NB + b) * NH + hh) * QP + (t >> 1)];

  const int lane = t & 63, w = t >> 6;
  const int fr = lane & 15, fq = lane >> 4;

  // ---------------- phase A: stage Ws once (96 rows x 256 k bf16, pitch 512B)
#pragma unroll
  for (int p = 0; p < 6; ++p) {
    const int c = p * 512 + t;
    const int r = c >> 5, ch = c & 31;
    const int mat = r >> 5, jj = r & 31;
    *(short8v*)(Ws + r * 512 + ((ch ^ (r & 7)) << 4)) =
        *(const short8v*)(WtL + ((size_t)mat * 256 + hh * 32 + jj) * 256 + ch * 8);
  }
  __syncthreads();

  // pf[n][m]: q/k TRANSPOSED (D row = kcol = fq*4+rr, D col = node = fr); n: q0 q1 k0 k1
  // po[m][n2]: v normal (D row = node = fq*4+rr, D col = vcol = fr)
  f32x4 pf[4][2] = {};
  f32x4 po[2][2] = {};
  const int hrow0 = bnode + w * 32;
#pragma unroll
  for (int kb = 0; kb < 2; ++kb) {
#pragma unroll
    for (int ks = 0; ks < 4; ++ks) {
      const int col0 = kb * 128 + (ks * 4 + fq) * 8;
      short8v hfrag[2];
#pragma unroll
      for (int m = 0; m < 2; ++m) {
        const float* src = hsrc + (size_t)(hrow0 + m * 16 + fr) * 256 + col0;
        const float4 v0 = *(const float4*)src;
        const float4 v1 = *(const float4*)(src + 4);
        short8v o;
        o[0] = f2b(v0.x * bnsc[col0 + 0] + bnsh[col0 + 0]);
        o[1] = f2b(v0.y * bnsc[col0 + 1] + bnsh[col0 + 1]);
        o[2] = f2b(v0.z * bnsc[col0 + 2] + bnsh[col0 + 2]);
        o[3] = f2b(v0.w * bnsc[col0 + 3] + bnsh[col0 + 3]);
        o[4] = f2b(v1.x * bnsc[col0 + 4] + bnsh[col0 + 4]);
        o[5] = f2b(v1.y * bnsc[col0 + 5] + bnsh[col0 + 5]);
        o[6] = f2b(v1.z * bnsc[col0 + 6] + bnsh[col0 + 6]);
        o[7] = f2b(v1.w * bnsc[col0 + 7] + bnsh[col0 + 7]);
        hfrag[m] = o;
      }
      short8v wfrag[6];
#pragma unroll
      for (int n = 0; n < 6; ++n) {
        const int rB = n * 16 + fr;
        wfrag[n] = *(const short8v*)(Ws + rB * 512 + (((kb * 16 + ks * 4 + fq) ^ (rB & 7)) << 4));
      }
#pragma unroll
      for (int n = 0; n < 4; ++n)
#pragma unroll
        for (int m = 0; m < 2; ++m)
          pf[n][m] = __builtin_amdgcn_mfma_f32_16x16x32_bf16(wfrag[n], hfrag[m], pf[n][m], 0, 0, 0);
#pragma unroll
      for (int m = 0; m < 2; ++m)
#pragma unroll
        for (int n2 = 0; n2 < 2; ++n2)
          po[m][n2] = __builtin_amdgcn_mfma_f32_16x16x32_bf16(hfrag[m], wfrag[4 + n2], po[m][n2], 0, 0, 0);
    }
  }
  __syncthreads();   // Ws dead; safe to write Ks / Vt / qtmp

  // ---------------- phase A epilogue: packed short4 scatters
  char* qtmp = Pw + w * 5120;   // 32 rows x 80B
  {
    const float* bqp = bq_l + hh * 32;
    const float* bkp = bk_l + hh * 32;
    const float* bvp = bv_l + hh * 32;
    // q (transposed acc): lane col = node = fr; rows = kcol = n*16 + fq*4 + rr
#pragma unroll
    for (int n = 0; n < 2; ++n) {
      const int kcol0 = n * 16 + fq * 4;
#pragma unroll
      for (int m = 0; m < 2; ++m) {
        const int nodel = m * 16 + fr;
        short4 pk;
        pk.x = f2b((pf[n][m][0] + bqp[kcol0 + 0]) * QSCALE);
        pk.y = f2b((pf[n][m][1] + bqp[kcol0 + 1]) * QSCALE);
        pk.z = f2b((pf[n][m][2] + bqp[kcol0 + 2]) * QSCALE);
        pk.w = f2b((pf[n][m][3] + bqp[kcol0 + 3]) * QSCALE);
        *(short4*)(qtmp + nodel * 80 + kcol0 * 2) = pk;
      }
    }
    // k (transposed acc) -> Ks cols 0..31
#pragma unroll
    for (int n = 0; n < 2; ++n) {
      const int kcol0 = n * 16 + fq * 4;
#pragma unroll
      for (int m = 0; m < 2; ++m) {
        const int node = w * 32 + m * 16 + fr;
        short4 pk;
        pk.x = f2b(pf[2 + n][m][0] + bkp[kcol0 + 0]);
        pk.y = f2b(pf[2 + n][m][1] + bkp[kcol0 + 1]);
        pk.z = f2b(pf[2 + n][m][2] + bkp[kcol0 + 2]);
        pk.w = f2b(pf[2 + n][m][3] + bkp[kcol0 + 3]);
        *(short4*)(Ks + node * 384 + (((kcol0 >> 3) ^ (node & 7)) << 4) + (kcol0 & 7) * 2) = pk;
      }
    }
    // v (normal acc): lane col = vcol = fr; rows = node = w*32 + m*16 + fq*4 + rr
#pragma unroll
    for (int m = 0; m < 2; ++m) {
      const int node0 = w * 32 + m * 16 + fq * 4;
#pragma unroll
      for (int n2 = 0; n2 < 2; ++n2) {
        const int vcol = n2 * 16 + fr;
        const float bvv = bvp[vcol];
        short4 pk;
        pk.x = f2b(po[m][n2][0] + bvv);
        pk.y = f2b(po[m][n2][1] + bvv);
        pk.z = f2b(po[m][n2][2] + bvv);
        pk.w = f2b(po[m][n2][3] + bvv);
        *(short4*)(Vt + vcol * 512 + (((node0 >> 3) ^ (vcol & 7)) << 4) + (node0 & 7) * 2) = pk;
      }
    }
  }
  // ---------------- phase B staging: phi.z -> Ks cols 32..159
  {
    const int r = t >> 1, half = t & 1;
    const short* zrow = zbf + (size_t)(bnode + r) * 128 + half * 64;
#pragma unroll
    for (int cc = 0; cc < 8; ++cc) {
      const short8v zv = *(const short8v*)(zrow + cc * 8);
      const int zc = half * 64 + cc * 8;
      short8v o;
#pragma unroll
      for (int e = 0; e < 8; ++e)
        o[e] = f2b(b2f((unsigned short)zv[e]) * ph2[zc + e]);
      const int c = 4 + half * 8 + cc;
      *(short8v*)(Ks + r * 384 + ((c ^ (r & 7)) << 4)) = o;
    }
  }
  __syncthreads();

  const int i0w = w * 32;
  // Q' fragments: ks0 = q (from qtmp), ks1..4 = plain z (bf16 direct)
  short8v Qf[2][5];
#pragma unroll
  for (int s = 0; s < 2; ++s) {
    Qf[s][0] = *(const short8v*)(qtmp + (s * 16 + fr) * 80 + fq * 16);
    const short* zr = zbf + (size_t)(bnode + i0w + s * 16 + fr) * 128;
#pragma unroll
    for (int ks = 1; ks < 5; ++ks)
      Qf[s][ks] = *(const short8v*)(zr + (ks - 1) * 32 + fq * 8);
  }

  // S^T = K' Q'^T : acc[s][jt] lane holds S[q = i0w+s*16+fr][j = jt*16+fq*4+rr]
  f32x4 acc[2][16] = {};
  __builtin_amdgcn_s_setprio(1);
#pragma unroll
  for (int ks = 0; ks < 5; ++ks) {
#pragma unroll
    for (int jt = 0; jt < 16; ++jt) {
      const int row = jt * 16 + fr;
      const short8v a = *(const short8v*)(Ks + row * 384 + (((ks * 4 + fq) ^ (row & 7)) << 4));
      acc[0][jt] = __builtin_amdgcn_mfma_f32_16x16x32_bf16(a, Qf[0][ks], acc[0][jt], 0, 0, 0);
      acc[1][jt] = __builtin_amdgcn_mfma_f32_16x16x32_bf16(a, Qf[1][ks], acc[1][jt], 0, 0, 0);
    }
  }
  __builtin_amdgcn_s_setprio(0);

  float rsv0, rsv1;
#pragma unroll
  for (int s = 0; s < 2; ++s) {
    float m = -1e30f;
#pragma unroll
    for (int jt = 0; jt < 16; ++jt)
#pragma unroll
      for (int rr = 0; rr < 4; ++rr) m = fmaxf(m, acc[s][jt][rr]);
    m = fmaxf(m, __shfl_xor(m, 16));
    m = fmaxf(m, __shfl_xor(m, 32));
    float sm = 0.f;
#pragma unroll
    for (int jt = 0; jt < 16; ++jt)
#pragma unroll
      for (int rr = 0; rr < 4; ++rr) {
        const float e = __expf(acc[s][jt][rr] - m);
        acc[s][jt][rr] = e;
        sm += e;
      }
    sm += __shfl_xor(sm, 16);
    sm += __shfl_xor(sm, 32);
    const float r = 1.0f / sm;
    if (s == 0) rsv0 = r; else rsv1 = r;
  }
  if (fq == 0) rs_l[w * 32 + fr] = rsv0;
  if (fq == 1) rs_l[w * 32 + 16 + fr] = rsv1;

  // PV: per 32-j step, round-trip P through double-buffered per-wave LDS (reuses qtmp area)
  f32x4 oac[2][2] = {};
  char* pw0 = Pw + w * 5120;
#pragma unroll
  for (int ks = 0; ks < 8; ++ks) {
    char* pw = pw0 + (ks & 1) * 2560;
#pragma unroll
    for (int s = 0; s < 2; ++s)
#pragma unroll
      for (int j2 = 0; j2 < 2; ++j2) {
        const int jt = ks * 2 + j2;
        short4 pk;
        pk.x = f2b(acc[s][jt][0]); pk.y = f2b(acc[s][jt][1]);
        pk.z = f2b(acc[s][jt][2]); pk.w = f2b(acc[s][jt][3]);
        *(short4*)(pw + (s * 16 + fr) * 80 + j2 * 32 + fq * 8) = pk;
      }
    asm volatile("s_waitcnt lgkmcnt(0)" ::: "memory");
    __builtin_amdgcn_sched_barrier(0);
    const short8v pa0 = *(const short8v*)(pw + fr * 80 + fq * 16);
    const short8v pa1 = *(const short8v*)(pw + (16 + fr) * 80 + fq * 16);
    const int sw = (((ks * 4 + fq) ^ (fr & 7)) << 4);
    const short8v vb0 = *(const short8v*)(Vt + fr * 512 + sw);
    const short8v vb1 = *(const short8v*)(Vt + (16 + fr) * 512 + sw);
    oac[0][0] = __builtin_amdgcn_mfma_f32_16x16x32_bf16(pa0, vb0, oac[0][0], 0, 0, 0);
    oac[0][1] = __builtin_amdgcn_mfma_f32_16x16x32_bf16(pa0, vb1, oac[0][1], 0, 0, 0);
    oac[1][0] = __builtin_amdgcn_mfma_f32_16x16x32_bf16(pa1, vb0, oac[1][0], 0, 0, 0);
    oac[1][1] = __builtin_amdgcn_mfma_f32_16x16x32_bf16(pa1, vb1, oac[1][1], 0, 0, 0);
  }

#pragma unroll
  for (int s = 0; s < 2; ++s)
#pragma unroll
    for (int rr = 0; rr < 4; ++rr) {
      const float rs = rs_l[w * 32 + s * 16 + fq * 4 + rr];
      const int node = bnode + i0w + s * 16 + fq * 4 + rr;
#pragma unroll
      for (int nt = 0; nt < 2; ++nt)
        obf[(size_t)node * 256 + hh * 32 + nt * 16 + fr] = f2b(oac[s][nt][rr] * rs);
    }
}

// ---------------------------------------------------------------- fused O-proj + residual(BN) + stats
__global__ __launch_bounds__(256) void k_projo(const short* __restrict__ Abf,
                                               const short* __restrict__ WtO,
                                               const float* __restrict__ bo,
                                               const float* __restrict__ hin,
                                               float* __restrict__ hout,
                                               const float* __restrict__ bnstat,
                                               const float* __restrict__ gamma,
                                               const float* __restrict__ beta,
                                               float* __restrict__ bna) {
  __shared__ __align__(16) short As[64 * 128];
  __shared__ __align__(16) short Bs[128 * 128];
  __shared__ float sred[2][128][2];
  __shared__ float bnsc[256], bnsh[256];
  const int t = threadIdx.x;
  const int m0 = blockIdx.x * 64;
  const int c0 = blockIdx.y * 128;
  const int lane = t & 63, w = t >> 6;
  const int wr = w >> 1, wc = w & 1;
  const int fr = lane & 15, fq = lane >> 4;

  bn_coeffs(bnstat, gamma, beta, bnsc, bnsh, t);

  f32x4 acc[2][4] = {};
  for (int kb = 0; kb < 2; ++kb) {
    __syncthreads();
#pragma unroll
    for (int p = 0; p < 4; ++p) {
      const int c = p * 256 + t;
      const int r = c >> 4, ch = c & 15;
      const int sw = ((ch ^ (r & 7)) << 4);
      *(short8v*)((char*)As + r * 256 + sw) =
          *(const short8v*)(Abf + (size_t)(m0 + r) * 256 + kb * 128 + ch * 8);
    }
#pragma unroll
    for (int p = 0; p < 8; ++p) {
      const int c = p * 256 + t;
      const int r = c >> 4, ch = c & 15;
      const int sw = ((ch ^ (r & 7)) << 4);
      *(short8v*)((char*)Bs + r * 256 + sw) =
          *(const short8v*)(WtO + (size_t)(c0 + r) * 256 + kb * 128 + ch * 8);
    }
    __syncthreads();
#pragma unroll
    for (int ks = 0; ks < 4; ++ks) {
      short8v a[2], bfrag[4];
#pragma unroll
      for (int m = 0; m < 2; ++m) {
        const int rA = wr * 32 + m * 16 + fr;
        a[m] = *(const short8v*)((const char*)As + rA * 256 + (((ks * 4 + fq) ^ (rA & 7)) << 4));
      }
#pragma unroll
      for (int n = 0; n < 4; ++n) {
        const int rB = wc * 64 + n * 16 + fr;
        bfrag[n] = *(const short8v*)((const char*)Bs + rB * 256 + (((ks * 4 + fq) ^ (rB & 7)) << 4));
      }
#pragma unroll
      for (int m = 0; m < 2; ++m)
#pragma unroll
        for (int n = 0; n < 4; ++n)
          acc[m][n] = __builtin_amdgcn_mfma_f32_16x16x32_bf16(a[m], bfrag[n], acc[m][n], 0, 0, 0);
    }
  }
#pragma unroll
  for (int n = 0; n < 4; ++n) {
    const int col = c0 + wc * 64 + n * 16 + fr;
    const float bv = bo[col];
    const float sc = bnsc[col], sh = bnsh[col];
    float s = 0.f, ss = 0.f;
#pragma unroll
    for (int m = 0; m < 2; ++m)
#pragma unroll
      for (int rr = 0; rr < 4; ++rr) {
        const int row = m0 + wr * 32 + m * 16 + fq * 4 + rr;
        const size_t idx = (size_t)row * 256 + col;
        const float v = acc[m][n][rr] + bv + (hin[idx] * sc + sh);
        hout[idx] = v;
        s += v;
        ss += v * v;
      }
    s += __shfl_xor(s, 16); s += __shfl_xor(s, 32);
    ss += __shfl_xor(ss, 16); ss += __shfl_xor(ss, 32);
    if (fq == 0) {
      sred[wr][wc * 64 + n * 16 + fr][0] = s;
      sred[wr][wc * 64 + n * 16 + fr][1] = ss;
    }
  }
  __syncthreads();
  if (t < 128) {
    const float s = sred[0][t][0] + sred[1][t][0];
    const float ss = sred[0][t][1] + sred[1][t][1];
    atomicAdd(&bna[c0 + t], s);
    atomicAdd(&bna[256 + c0 + t], ss);
  }
}

// ---------------------------------------------------------------- BN apply (final layer -> out), float4
__global__ __launch_bounds__(256) void k_bn_apply(const float* __restrict__ h,
                                                  const float* __restrict__ accum,
                                                  const float* __restrict__ gamma,
                                                  const float* __restrict__ beta,
                                                  float* __restrict__ outp, int l) {
  const int i4 = blockIdx.x * 256 + threadIdx.x;          // over HD2/4
  const int c0 = (i4 << 2) & 255;
  const float4 v = ((const float4*)h)[i4];
  float vv[4] = {v.x, v.y, v.z, v.w};
  float o[4];
#pragma unroll
  for (int e = 0; e < 4; ++e) {
    const int col = c0 + e;
    const float mean = accum[col] * (1.0f / NT);
    const float var = accum[DD + col] * (1.0f / NT) - mean * mean;
    o[e] = (vv[e] - mean) * rsqrtf(var + 1e-5f) * gamma[l * DD + col] + beta[l * DD + col];
  }
  ((float4*)outp)[i4] = make_float4(o[0], o[1], o[2], o[3]);
}

// ================================================================ host
extern "C" void kernel_launch(void* const* d_in, const int* in_sizes, int n_in,
                              void* d_out, int out_size, void* d_ws, size_t ws_size,
                              hipStream_t stream) {
  (void)in_sizes; (void)n_in; (void)out_size; (void)ws_size;
  const float* x    = (const float*)d_in[0];
  const float* z    = (const float*)d_in[1];
  const float* Lam  = (const float*)d_in[2];
  const float* Wq   = (const float*)d_in[4];
  const float* Wk   = (const float*)d_in[5];
  const float* Wv   = (const float*)d_in[6];
  const float* Wo   = (const float*)d_in[7];
  const float* bq   = (const float*)d_in[8];
  const float* bk   = (const float*)d_in[9];
  const float* bv   = (const float*)d_in[10];
  const float* bo   = (const float*)d_in[11];
  const float* pW1  = (const float*)d_in[12];
  const float* pb1  = (const float*)d_in[13];
  const float* pW2  = (const float*)d_in[14];
  const float* pb2  = (const float*)d_in[15];
  const float* gam  = (const float*)d_in[16];
  const float* bet  = (const float*)d_in[17];
  float* out = (float*)d_out;

  float* h    = (float*)d_ws;                 // 8 MB fp32 running h (pre-BN)
  short* obf  = (short*)(h + HD2);            // attn out bf16 (4 MB)
  short* zbf  = obf + HD2;                    // 2 MB bf16 z
  short* Wt   = zbf + NT * 128;               // 2 MB (16 mats x 256x256 bf16)
  float* phiA = (float*)(Wt + 16 * DD * DD);  // 32 KB
  float* bna  = phiA + 4 * NB * NH * QP;      // 4 layers x 512

  k_setup<<<1024, 256, 0, stream>>>(z, out + HD2, zbf, bna, Lam, pW1, pb1, pW2, pb2,
                                    phiA, Wq, Wk, Wv, Wo, Wt);
  for (int l = 0; l < 4; ++l) {
    const float* bnprev = l ? bna + (l - 1) * 512 : nullptr;
    const float* gprev  = gam + (l ? (l - 1) * DD : 0);
    const float* bprev  = bet + (l ? (l - 1) * DD : 0);
    const float* hsrc   = l ? h : x;
    k_fat<<<256, 512, 0, stream>>>(hsrc, Wt + (size_t)l * 4 * DD * DD,
                                   bnprev, gprev, bprev,
                                   bq + l * DD, bk + l * DD, bv + l * DD,
                                   zbf, phiA, obf, l);
    k_projo<<<dim3(128, 2), 256, 0, stream>>>(obf, Wt + (size_t)(l * 4 + 3) * DD * DD,
                                              bo + l * DD, hsrc, h,
                                              bnprev, gprev, bprev, bna + l * 512);
  }
  k_bn_apply<<<2048, 256, 0, stream>>>(h, bna + 3 * 512, gam, bet, out, 3);
}

// Round 14
// 140.586 us; speedup vs baseline: 1.0634x; 1.0634x over previous
//
#include <hip/hip_runtime.h>
#include <hip/hip_bf16.h>

typedef __hip_bfloat16 bf16;
typedef __attribute__((ext_vector_type(8))) short short8v;   // 8 bf16 (4 VGPRs)
typedef __attribute__((ext_vector_type(4))) float f32x4;

constexpr int NB  = 32;
constexpr int NM  = 256;
constexpr int DD  = 256;
constexpr int NH  = 8;
constexpr int QP  = 64;
constexpr int FF  = 32;
constexpr int NT  = NB * NM;        // 8192
constexpr int HD2 = NT * DD;        // 2097152
constexpr float QSCALE = 0.17677669529663687f;

__device__ __forceinline__ float b2f(unsigned short u) {
  return __uint_as_float(((unsigned)u) << 16);
}
__device__ __forceinline__ short f2b(float f) {
  union { bf16 h; short s; } u;
  u.h = __float2bfloat16(f);
  return u.s;
}

__device__ __forceinline__ void bn_coeffs(const float* bnstat, const float* gamma,
                                          const float* beta, float* bnsc, float* bnsh,
                                          int t) {
  if (t < 256) {
    float sc = 1.f, sh = 0.f;
    if (bnstat) {
      const float mean = bnstat[t] * (1.0f / NT);
      const float var = bnstat[256 + t] * (1.0f / NT) - mean * mean;
      const float rstd = rsqrtf(var + 1e-5f);
      sc = rstd * gamma[t];
      sh = beta[t] - mean * sc;
    }
    bnsc[t] = sc; bnsh[t] = sh;
  }
}

// ---------------------------------------------------------------- setup: z copy/zbf, bna, phi, Wt
__global__ __launch_bounds__(256) void k_setup(const float* __restrict__ z,
                                               float* __restrict__ outz,
                                               short* __restrict__ zbf,
                                               float* __restrict__ bna,
                                               const float* __restrict__ Lam,
                                               const float* __restrict__ pW1,
                                               const float* __restrict__ pb1,
                                               const float* __restrict__ pW2,
                                               const float* __restrict__ pb2,
                                               float* __restrict__ phiA,
                                               const float* __restrict__ Wq,
                                               const float* __restrict__ Wk,
                                               const float* __restrict__ Wv,
                                               const float* __restrict__ Wo,
                                               short* __restrict__ Wt) {
  __shared__ float Ts[32][33];
  const int t = threadIdx.x;
  const int idx = blockIdx.x * 256 + t;                   // 262144 float4s of z
  {
    const float4 v = ((const float4*)z)[idx];
    ((float4*)outz)[idx] = v;
    short4 s;
    s.x = f2b(v.x); s.y = f2b(v.y); s.z = f2b(v.z); s.w = f2b(v.w);
    ((short4*)zbf)[idx] = s;
  }
  if (idx < 4 * 512) bna[idx] = 0.f;
  if (idx < 4 * 2048) {                                   // phi MLP, all layers
    const int l = idx >> 11;
    const int t2 = idx & 2047;
    const int b = t2 >> 6, qp = t2 & 63;
    const float lam = Lam[b * QP + qp];
    const float* w1 = pW1 + l * FF;
    const float* bb1 = pb1 + l * FF;
    const float* w2 = pW2 + l * FF * NH;
    const float* bb2 = pb2 + l * NH;
    float acc[NH];
#pragma unroll
    for (int h = 0; h < NH; ++h) acc[h] = bb2[h];
    for (int f = 0; f < FF; ++f) {
      float a = lam * w1[f] + bb1[f];
      a = a > 0.f ? a : 0.f;
#pragma unroll
      for (int h = 0; h < NH; ++h) acc[h] += a * w2[f * NH + h];
    }
#pragma unroll
    for (int h = 0; h < NH; ++h)
      phiA[(((size_t)l * NB + b) * NH + h) * QP + qp] = acc[h];
  }
  if (blockIdx.x < 128) {                                 // Wt transpose
    const int mat = blockIdx.x >> 3;                      // 16 matrices
    const int l = mat >> 2, wsel = mat & 3;
    const float* W = (wsel == 0 ? Wq : wsel == 1 ? Wk : wsel == 2 ? Wv : Wo) + l * DD * DD;
    const int j0 = (blockIdx.x & 7) * 32;
    short* outw = Wt + (size_t)mat * DD * DD;
    const int jj = t & 31, kk8 = t >> 5;
    for (int k0 = 0; k0 < DD; k0 += 32) {
      __syncthreads();
#pragma unroll
      for (int s = 0; s < 4; ++s) {
        const int kl = s * 8 + kk8;
        Ts[kl][jj] = W[(k0 + kl) * DD + j0 + jj];
      }
      __syncthreads();
#pragma unroll
      for (int s = 0; s < 4; ++s) {
        const int jl = (t >> 5) + s * 8;
        const int kl = t & 31;
        outw[(size_t)(j0 + jl) * DD + k0 + kl] = f2b(Ts[kl][jl]);
      }
    }
  }
}

// ---------------------------------------------------------------- fused qkv-proj + bias + attention
// One block per (b,h) (XCD swizzle), 512 threads = 8 waves.
// Phase A: q/k/v = BN(h) @ W-slices (MFMA; q,k computed transposed for packed scatter).
// Phase B: S = Q'K'^T with Q'=[q*scale, z], K'=[k, phi.z]; softmax; PV.
__global__ __launch_bounds__(512, 2) void k_fat(const float* __restrict__ hsrc,
                                                const short* __restrict__ WtL,   // layer base (4 mats)
                                                const float* __restrict__ bnstat,
                                                const float* __restrict__ gamma,
                                                const float* __restrict__ beta,
                                                const float* __restrict__ bq_l,
                                                const float* __restrict__ bk_l,
                                                const float* __restrict__ bv_l,
                                                const short* __restrict__ zbf,
                                                const float* __restrict__ phiAll,
                                                short* __restrict__ obf, int l) {
  // LDS map (159232 B total):
  //  [0, 98304)        Ks: K'[256 rows][384B pitch] -- phase A overlays Hs(64KB)+Ws(24KB) here
  //  [98304, 114688)   Vt: V^T[32][512B]
  //  [114688, 155648)  Pw: 8 waves x 5120B (qtmp 2560 + PV double-buffer)
  //  [155648, 156672)  rs_l (256 f32)
  //  [156672, 157184)  ph2 (128 f32)
  //  [157184, 159232)  bnsc/bnsh (256+256 f32)
  __shared__ __align__(16) char SM[159232];
  char* Ks = SM;
  char* Hs = SM;                      // phase A alias
  char* Ws = SM + 65536;              // phase A alias
  char* Vt = SM + 98304;
  char* Pw = SM + 114688;
  float* rs_l = (float*)(SM + 155648);
  float* ph2  = (float*)(SM + 156672);
  float* bnsc = (float*)(SM + 157184);
  float* bnsh = bnsc + 256;

  const int t = threadIdx.x;
  const int bh = (blockIdx.x & 7) * 32 + (blockIdx.x >> 3);   // XCD swizzle
  const int b = bh >> 3, hh = bh & 7;
  const int bnode = b * 256;

  bn_coeffs(bnstat, gamma, beta, bnsc, bnsh, t);
  if (t < 128)
    ph2[t] = phiAll[(((size_t)l * NB + b) * NH + hh) * QP + (t >> 1)];

  const int lane = t & 63, w = t >> 6;
  const int fr = lane & 15, fq = lane >> 4;

  // ---------------- phase A: qkv projection (wave w owns nodes w*32..w*32+32)
  // pf[n][m]: q/k TRANSPOSED (D row = kcol = fq*4+rr, D col = node = fr); n: q0 q1 k0 k1
  // po[m][n2]: v normal (D row = node = fq*4+rr, D col = vcol = fr)
  f32x4 pf[4][2] = {};
  f32x4 po[2][2] = {};
  for (int kb = 0; kb < 2; ++kb) {
    __syncthreads();
    // stage Hs: 256 rows x 128 cols bf16 (BN applied), pitch 256B, swizzled
#pragma unroll
    for (int p = 0; p < 8; ++p) {
      const int c = p * 512 + t;
      const int r = c >> 4, ch = c & 15;
      const int col0 = kb * 128 + ch * 8;
      const float* src = hsrc + (size_t)(bnode + r) * 256 + col0;
      const float4 v0 = *(const float4*)src;
      const float4 v1 = *(const float4*)(src + 4);
      short8v o;
      o[0] = f2b(v0.x * bnsc[col0 + 0] + bnsh[col0 + 0]);
      o[1] = f2b(v0.y * bnsc[col0 + 1] + bnsh[col0 + 1]);
      o[2] = f2b(v0.z * bnsc[col0 + 2] + bnsh[col0 + 2]);
      o[3] = f2b(v0.w * bnsc[col0 + 3] + bnsh[col0 + 3]);
      o[4] = f2b(v1.x * bnsc[col0 + 4] + bnsh[col0 + 4]);
      o[5] = f2b(v1.y * bnsc[col0 + 5] + bnsh[col0 + 5]);
      o[6] = f2b(v1.z * bnsc[col0 + 6] + bnsh[col0 + 6]);
      o[7] = f2b(v1.w * bnsc[col0 + 7] + bnsh[col0 + 7]);
      *(short8v*)(Hs + r * 256 + ((ch ^ (r & 7)) << 4)) = o;
    }
    // stage Ws: 96 rows (q/k/v slices for head hh) x 128 k, pitch 256B, swizzled
#pragma unroll
    for (int p = 0; p < 3; ++p) {
      const int c = p * 512 + t;
      const int r = c >> 4, ch = c & 15;
      const int mat = r >> 5, jj = r & 31;
      *(short8v*)(Ws + r * 256 + ((ch ^ (r & 7)) << 4)) =
          *(const short8v*)(WtL + ((size_t)mat * 256 + hh * 32 + jj) * 256 + kb * 128 + ch * 8);
    }
    __syncthreads();
#pragma unroll
    for (int ks = 0; ks < 4; ++ks) {
      short8v hfrag[2], wfrag[6];
#pragma unroll
      for (int m = 0; m < 2; ++m) {
        const int rA = w * 32 + m * 16 + fr;
        hfrag[m] = *(const short8v*)(Hs + rA * 256 + (((ks * 4 + fq) ^ (rA & 7)) << 4));
      }
#pragma unroll
      for (int n = 0; n < 6; ++n) {
        const int rB = n * 16 + fr;
        wfrag[n] = *(const short8v*)(Ws + rB * 256 + (((ks * 4 + fq) ^ (rB & 7)) << 4));
      }
#pragma unroll
      for (int n = 0; n < 4; ++n)
#pragma unroll
        for (int m = 0; m < 2; ++m)
          pf[n][m] = __builtin_amdgcn_mfma_f32_16x16x32_bf16(wfrag[n], hfrag[m], pf[n][m], 0, 0, 0);
#pragma unroll
      for (int m = 0; m < 2; ++m)
#pragma unroll
        for (int n2 = 0; n2 < 2; ++n2)
          po[m][n2] = __builtin_amdgcn_mfma_f32_16x16x32_bf16(hfrag[m], wfrag[4 + n2], po[m][n2], 0, 0, 0);
    }
  }
  __syncthreads();   // Hs/Ws dead; safe to overlay Ks

  // ---------------- phase A epilogue: packed short4 scatters
  char* qtmp = Pw + w * 5120;   // 32 rows x 80B
  {
    const float* bqp = bq_l + hh * 32;
    const float* bkp = bk_l + hh * 32;
    const float* bvp = bv_l + hh * 32;
    // q (transposed acc): lane col = node = fr; rows = kcol = n*16 + fq*4 + rr
#pragma unroll
    for (int n = 0; n < 2; ++n) {
      const int kcol0 = n * 16 + fq * 4;
#pragma unroll
      for (int m = 0; m < 2; ++m) {
        const int nodel = m * 16 + fr;
        short4 pk;
        pk.x = f2b((pf[n][m][0] + bqp[kcol0 + 0]) * QSCALE);
        pk.y = f2b((pf[n][m][1] + bqp[kcol0 + 1]) * QSCALE);
        pk.z = f2b((pf[n][m][2] + bqp[kcol0 + 2]) * QSCALE);
        pk.w = f2b((pf[n][m][3] + bqp[kcol0 + 3]) * QSCALE);
        *(short4*)(qtmp + nodel * 80 + kcol0 * 2) = pk;
      }
    }
    // k (transposed acc) -> Ks cols 0..31
#pragma unroll
    for (int n = 0; n < 2; ++n) {
      const int kcol0 = n * 16 + fq * 4;
#pragma unroll
      for (int m = 0; m < 2; ++m) {
        const int node = w * 32 + m * 16 + fr;
        short4 pk;
        pk.x = f2b(pf[2 + n][m][0] + bkp[kcol0 + 0]);
        pk.y = f2b(pf[2 + n][m][1] + bkp[kcol0 + 1]);
        pk.z = f2b(pf[2 + n][m][2] + bkp[kcol0 + 2]);
        pk.w = f2b(pf[2 + n][m][3] + bkp[kcol0 + 3]);
        *(short4*)(Ks + node * 384 + (((kcol0 >> 3) ^ (node & 7)) << 4) + (kcol0 & 7) * 2) = pk;
      }
    }
    // v (normal acc): lane col = vcol = fr; rows = node = w*32 + m*16 + fq*4 + rr
#pragma unroll
    for (int m = 0; m < 2; ++m) {
      const int node0 = w * 32 + m * 16 + fq * 4;
#pragma unroll
      for (int n2 = 0; n2 < 2; ++n2) {
        const int vcol = n2 * 16 + fr;
        const float bvv = bvp[vcol];
        short4 pk;
        pk.x = f2b(po[m][n2][0] + bvv);
        pk.y = f2b(po[m][n2][1] + bvv);
        pk.z = f2b(po[m][n2][2] + bvv);
        pk.w = f2b(po[m][n2][3] + bvv);
        *(short4*)(Vt + vcol * 512 + (((node0 >> 3) ^ (vcol & 7)) << 4) + (node0 & 7) * 2) = pk;
      }
    }
  }
  // ---------------- phase B staging: phi.z -> Ks cols 32..159
  {
    const int r = t >> 1, half = t & 1;
    const short* zrow = zbf + (size_t)(bnode + r) * 128 + half * 64;
#pragma unroll
    for (int cc = 0; cc < 8; ++cc) {
      const short8v zv = *(const short8v*)(zrow + cc * 8);
      const int zc = half * 64 + cc * 8;
      short8v o;
#pragma unroll
      for (int e = 0; e < 8; ++e)
        o[e] = f2b(b2f((unsigned short)zv[e]) * ph2[zc + e]);
      const int c = 4 + half * 8 + cc;
      *(short8v*)(Ks + r * 384 + ((c ^ (r & 7)) << 4)) = o;
    }
  }
  __syncthreads();

  const int i0w = w * 32;
  // Q' fragments: ks0 = q (from qtmp), ks1..4 = plain z (bf16 direct)
  short8v Qf[2][5];
#pragma unroll
  for (int s = 0; s < 2; ++s) {
    Qf[s][0] = *(const short8v*)(qtmp + (s * 16 + fr) * 80 + fq * 16);
    const short* zr = zbf + (size_t)(bnode + i0w + s * 16 + fr) * 128;
#pragma unroll
    for (int ks = 1; ks < 5; ++ks)
      Qf[s][ks] = *(const short8v*)(zr + (ks - 1) * 32 + fq * 8);
  }

  // S^T = K' Q'^T : acc[s][jt] lane holds S[q = i0w+s*16+fr][j = jt*16+fq*4+rr]
  f32x4 acc[2][16] = {};
  __builtin_amdgcn_s_setprio(1);
#pragma unroll
  for (int ks = 0; ks < 5; ++ks) {
#pragma unroll
    for (int jt = 0; jt < 16; ++jt) {
      const int row = jt * 16 + fr;
      const short8v a = *(const short8v*)(Ks + row * 384 + (((ks * 4 + fq) ^ (row & 7)) << 4));
      acc[0][jt] = __builtin_amdgcn_mfma_f32_16x16x32_bf16(a, Qf[0][ks], acc[0][jt], 0, 0, 0);
      acc[1][jt] = __builtin_amdgcn_mfma_f32_16x16x32_bf16(a, Qf[1][ks], acc[1][jt], 0, 0, 0);
    }
  }
  __builtin_amdgcn_s_setprio(0);

  float rsv0, rsv1;
#pragma unroll
  for (int s = 0; s < 2; ++s) {
    float m = -1e30f;
#pragma unroll
    for (int jt = 0; jt < 16; ++jt)
#pragma unroll
      for (int rr = 0; rr < 4; ++rr) m = fmaxf(m, acc[s][jt][rr]);
    m = fmaxf(m, __shfl_xor(m, 16));
    m = fmaxf(m, __shfl_xor(m, 32));
    float sm = 0.f;
#pragma unroll
    for (int jt = 0; jt < 16; ++jt)
#pragma unroll
      for (int rr = 0; rr < 4; ++rr) {
        const float e = __expf(acc[s][jt][rr] - m);
        acc[s][jt][rr] = e;
        sm += e;
      }
    sm += __shfl_xor(sm, 16);
    sm += __shfl_xor(sm, 32);
    const float r = 1.0f / sm;
    if (s == 0) rsv0 = r; else rsv1 = r;
  }
  if (fq == 0) rs_l[w * 32 + fr] = rsv0;
  if (fq == 1) rs_l[w * 32 + 16 + fr] = rsv1;

  // PV: per 32-j step, round-trip P through double-buffered per-wave LDS (reuses qtmp area)
  f32x4 oac[2][2] = {};
  char* pw0 = Pw + w * 5120;
#pragma unroll
  for (int ks = 0; ks < 8; ++ks) {
    char* pw = pw0 + (ks & 1) * 2560;
#pragma unroll
    for (int s = 0; s < 2; ++s)
#pragma unroll
      for (int j2 = 0; j2 < 2; ++j2) {
        const int jt = ks * 2 + j2;
        short4 pk;
        pk.x = f2b(acc[s][jt][0]); pk.y = f2b(acc[s][jt][1]);
        pk.z = f2b(acc[s][jt][2]); pk.w = f2b(acc[s][jt][3]);
        *(short4*)(pw + (s * 16 + fr) * 80 + j2 * 32 + fq * 8) = pk;
      }
    asm volatile("s_waitcnt lgkmcnt(0)" ::: "memory");
    __builtin_amdgcn_sched_barrier(0);
    const short8v pa0 = *(const short8v*)(pw + fr * 80 + fq * 16);
    const short8v pa1 = *(const short8v*)(pw + (16 + fr) * 80 + fq * 16);
    const int sw = (((ks * 4 + fq) ^ (fr & 7)) << 4);
    const short8v vb0 = *(const short8v*)(Vt + fr * 512 + sw);
    const short8v vb1 = *(const short8v*)(Vt + (16 + fr) * 512 + sw);
    oac[0][0] = __builtin_amdgcn_mfma_f32_16x16x32_bf16(pa0, vb0, oac[0][0], 0, 0, 0);
    oac[0][1] = __builtin_amdgcn_mfma_f32_16x16x32_bf16(pa0, vb1, oac[0][1], 0, 0, 0);
    oac[1][0] = __builtin_amdgcn_mfma_f32_16x16x32_bf16(pa1, vb0, oac[1][0], 0, 0, 0);
    oac[1][1] = __builtin_amdgcn_mfma_f32_16x16x32_bf16(pa1, vb1, oac[1][1], 0, 0, 0);
  }

#pragma unroll
  for (int s = 0; s < 2; ++s)
#pragma unroll
    for (int rr = 0; rr < 4; ++rr) {
      const float rs = rs_l[w * 32 + s * 16 + fq * 4 + rr];
      const int node = bnode + i0w + s * 16 + fq * 4 + rr;
#pragma unroll
      for (int nt = 0; nt < 2; ++nt)
        obf[(size_t)node * 256 + hh * 32 + nt * 16 + fr] = f2b(oac[s][nt][rr] * rs);
    }
}

// ---------------------------------------------------------------- fused O-proj + residual(BN) + stats
__global__ __launch_bounds__(256) void k_projo(const short* __restrict__ Abf,
                                               const short* __restrict__ WtO,
                                               const float* __restrict__ bo,
                                               const float* __restrict__ hin,
                                               float* __restrict__ hout,
                                               const float* __restrict__ bnstat,
                                               const float* __restrict__ gamma,
                                               const float* __restrict__ beta,
                                               float* __restrict__ bna) {
  __shared__ __align__(16) short As[64 * 128];
  __shared__ __align__(16) short Bs[128 * 128];
  __shared__ float sred[2][128][2];
  __shared__ float bnsc[256], bnsh[256];
  const int t = threadIdx.x;
  const int m0 = blockIdx.x * 64;
  const int c0 = blockIdx.y * 128;
  const int lane = t & 63, w = t >> 6;
  const int wr = w >> 1, wc = w & 1;
  const int fr = lane & 15, fq = lane >> 4;

  bn_coeffs(bnstat, gamma, beta, bnsc, bnsh, t);

  f32x4 acc[2][4] = {};
  for (int kb = 0; kb < 2; ++kb) {
    __syncthreads();
#pragma unroll
    for (int p = 0; p < 4; ++p) {
      const int c = p * 256 + t;
      const int r = c >> 4, ch = c & 15;
      const int sw = ((ch ^ (r & 7)) << 4);
      *(short8v*)((char*)As + r * 256 + sw) =
          *(const short8v*)(Abf + (size_t)(m0 + r) * 256 + kb * 128 + ch * 8);
    }
#pragma unroll
    for (int p = 0; p < 8; ++p) {
      const int c = p * 256 + t;
      const int r = c >> 4, ch = c & 15;
      const int sw = ((ch ^ (r & 7)) << 4);
      *(short8v*)((char*)Bs + r * 256 + sw) =
          *(const short8v*)(WtO + (size_t)(c0 + r) * 256 + kb * 128 + ch * 8);
    }
    __syncthreads();
#pragma unroll
    for (int ks = 0; ks < 4; ++ks) {
      short8v a[2], bfrag[4];
#pragma unroll
      for (int m = 0; m < 2; ++m) {
        const int rA = wr * 32 + m * 16 + fr;
        a[m] = *(const short8v*)((const char*)As + rA * 256 + (((ks * 4 + fq) ^ (rA & 7)) << 4));
      }
#pragma unroll
      for (int n = 0; n < 4; ++n) {
        const int rB = wc * 64 + n * 16 + fr;
        bfrag[n] = *(const short8v*)((const char*)Bs + rB * 256 + (((ks * 4 + fq) ^ (rB & 7)) << 4));
      }
#pragma unroll
      for (int m = 0; m < 2; ++m)
#pragma unroll
        for (int n = 0; n < 4; ++n)
          acc[m][n] = __builtin_amdgcn_mfma_f32_16x16x32_bf16(a[m], bfrag[n], acc[m][n], 0, 0, 0);
    }
  }
#pragma unroll
  for (int n = 0; n < 4; ++n) {
    const int col = c0 + wc * 64 + n * 16 + fr;
    const float bv = bo[col];
    const float sc = bnsc[col], sh = bnsh[col];
    float s = 0.f, ss = 0.f;
#pragma unroll
    for (int m = 0; m < 2; ++m)
#pragma unroll
      for (int rr = 0; rr < 4; ++rr) {
        const int row = m0 + wr * 32 + m * 16 + fq * 4 + rr;
        const size_t idx = (size_t)row * 256 + col;
        const float v = acc[m][n][rr] + bv + (hin[idx] * sc + sh);
        hout[idx] = v;
        s += v;
        ss += v * v;
      }
    s += __shfl_xor(s, 16); s += __shfl_xor(s, 32);
    ss += __shfl_xor(ss, 16); ss += __shfl_xor(ss, 32);
    if (fq == 0) {
      sred[wr][wc * 64 + n * 16 + fr][0] = s;
      sred[wr][wc * 64 + n * 16 + fr][1] = ss;
    }
  }
  __syncthreads();
  if (t < 128) {
    const float s = sred[0][t][0] + sred[1][t][0];
    const float ss = sred[0][t][1] + sred[1][t][1];
    atomicAdd(&bna[c0 + t], s);
    atomicAdd(&bna[256 + c0 + t], ss);
  }
}

// ---------------------------------------------------------------- BN apply (final layer -> out), float4
__global__ __launch_bounds__(256) void k_bn_apply(const float* __restrict__ h,
                                                  const float* __restrict__ accum,
                                                  const float* __restrict__ gamma,
                                                  const float* __restrict__ beta,
                                                  float* __restrict__ outp, int l) {
  const int i4 = blockIdx.x * 256 + threadIdx.x;          // over HD2/4
  const int c0 = (i4 << 2) & 255;
  const float4 v = ((const float4*)h)[i4];
  float vv[4] = {v.x, v.y, v.z, v.w};
  float o[4];
#pragma unroll
  for (int e = 0; e < 4; ++e) {
    const int col = c0 + e;
    const float mean = accum[col] * (1.0f / NT);
    const float var = accum[DD + col] * (1.0f / NT) - mean * mean;
    o[e] = (vv[e] - mean) * rsqrtf(var + 1e-5f) * gamma[l * DD + col] + beta[l * DD + col];
  }
  ((float4*)outp)[i4] = make_float4(o[0], o[1], o[2], o[3]);
}

// ================================================================ host
extern "C" void kernel_launch(void* const* d_in, const int* in_sizes, int n_in,
                              void* d_out, int out_size, void* d_ws, size_t ws_size,
                              hipStream_t stream) {
  (void)in_sizes; (void)n_in; (void)out_size; (void)ws_size;
  const float* x    = (const float*)d_in[0];
  const float* z    = (const float*)d_in[1];
  const float* Lam  = (const float*)d_in[2];
  const float* Wq   = (const float*)d_in[4];
  const float* Wk   = (const float*)d_in[5];
  const float* Wv   = (const float*)d_in[6];
  const float* Wo   = (const float*)d_in[7];
  const float* bq   = (const float*)d_in[8];
  const float* bk   = (const float*)d_in[9];
  const float* bv   = (const float*)d_in[10];
  const float* bo   = (const float*)d_in[11];
  const float* pW1  = (const float*)d_in[12];
  const float* pb1  = (const float*)d_in[13];
  const float* pW2  = (const float*)d_in[14];
  const float* pb2  = (const float*)d_in[15];
  const float* gam  = (const float*)d_in[16];
  const float* bet  = (const float*)d_in[17];
  float* out = (float*)d_out;

  float* h    = (float*)d_ws;                 // 8 MB fp32 running h (pre-BN)
  short* obf  = (short*)(h + HD2);            // attn out bf16 (4 MB)
  short* zbf  = obf + HD2;                    // 2 MB bf16 z
  short* Wt   = zbf + NT * 128;               // 2 MB (16 mats x 256x256 bf16)
  float* phiA = (float*)(Wt + 16 * DD * DD);  // 32 KB
  float* bna  = phiA + 4 * NB * NH * QP;      // 4 layers x 512

  k_setup<<<1024, 256, 0, stream>>>(z, out + HD2, zbf, bna, Lam, pW1, pb1, pW2, pb2,
                                    phiA, Wq, Wk, Wv, Wo, Wt);
  for (int l = 0; l < 4; ++l) {
    const float* bnprev = l ? bna + (l - 1) * 512 : nullptr;
    const float* gprev  = gam + (l ? (l - 1) * DD : 0);
    const float* bprev  = bet + (l ? (l - 1) * DD : 0);
    const float* hsrc   = l ? h : x;
    k_fat<<<256, 512, 0, stream>>>(hsrc, Wt + (size_t)l * 4 * DD * DD,
                                   bnprev, gprev, bprev,
                                   bq + l * DD, bk + l * DD, bv + l * DD,
                                   zbf, phiA, obf, l);
    k_projo<<<dim3(128, 2), 256, 0, stream>>>(obf, Wt + (size_t)(l * 4 + 3) * DD * DD,
                                              bo + l * DD, hsrc, h,
                                              bnprev, gprev, bprev, bna + l * 512);
  }
  k_bn_apply<<<2048, 256, 0, stream>>>(h, bna + 3 * 512, gam, bet, out, 3);
}

// Round 15
// 138.780 us; speedup vs baseline: 1.0772x; 1.0130x over previous
//
#include <hip/hip_runtime.h>
#include <hip/hip_bf16.h>

typedef __hip_bfloat16 bf16;
typedef __attribute__((ext_vector_type(8))) short short8v;   // 8 bf16 (4 VGPRs)
typedef __attribute__((ext_vector_type(4))) float f32x4;

constexpr int NB  = 32;
constexpr int NM  = 256;
constexpr int DD  = 256;
constexpr int NH  = 8;
constexpr int QP  = 64;
constexpr int FF  = 32;
constexpr int NT  = NB * NM;        // 8192
constexpr int HD2 = NT * DD;        // 2097152
constexpr float QSCALE = 0.17677669529663687f;

__device__ __forceinline__ float b2f(unsigned short u) {
  return __uint_as_float(((unsigned)u) << 16);
}
__device__ __forceinline__ short f2b(float f) {
  union { bf16 h; short s; } u;
  u.h = __float2bfloat16(f);
  return u.s;
}

__device__ __forceinline__ void bn_coeffs(const float* bnstat, const float* gamma,
                                          const float* beta, float* bnsc, float* bnsh,
                                          int t) {
  if (t < 256) {
    float sc = 1.f, sh = 0.f;
    if (bnstat) {
      const float mean = bnstat[t] * (1.0f / NT);
      const float var = bnstat[256 + t] * (1.0f / NT) - mean * mean;
      const float rstd = rsqrtf(var + 1e-5f);
      sc = rstd * gamma[t];
      sh = beta[t] - mean * sc;
    }
    bnsc[t] = sc; bnsh[t] = sh;
  }
}

// ---------------------------------------------------------------- setup: z copy/zbf, bna, phi, Wt
__global__ __launch_bounds__(256) void k_setup(const float* __restrict__ z,
                                               float* __restrict__ outz,
                                               short* __restrict__ zbf,
                                               float* __restrict__ bna,
                                               const float* __restrict__ Lam,
                                               const float* __restrict__ pW1,
                                               const float* __restrict__ pb1,
                                               const float* __restrict__ pW2,
                                               const float* __restrict__ pb2,
                                               float* __restrict__ phiA,
                                               const float* __restrict__ Wq,
                                               const float* __restrict__ Wk,
                                               const float* __restrict__ Wv,
                                               const float* __restrict__ Wo,
                                               short* __restrict__ Wt) {
  __shared__ float Ts[32][33];
  const int t = threadIdx.x;
  const int idx = blockIdx.x * 256 + t;                   // 262144 float4s of z
  {
    const float4 v = ((const float4*)z)[idx];
    ((float4*)outz)[idx] = v;
    short4 s;
    s.x = f2b(v.x); s.y = f2b(v.y); s.z = f2b(v.z); s.w = f2b(v.w);
    ((short4*)zbf)[idx] = s;
  }
  if (idx < 4 * 512) bna[idx] = 0.f;
  if (idx < 4 * 2048) {                                   // phi MLP, all layers
    const int l = idx >> 11;
    const int t2 = idx & 2047;
    const int b = t2 >> 6, qp = t2 & 63;
    const float lam = Lam[b * QP + qp];
    const float* w1 = pW1 + l * FF;
    const float* bb1 = pb1 + l * FF;
    const float* w2 = pW2 + l * FF * NH;
    const float* bb2 = pb2 + l * NH;
    float acc[NH];
#pragma unroll
    for (int h = 0; h < NH; ++h) acc[h] = bb2[h];
    for (int f = 0; f < FF; ++f) {
      float a = lam * w1[f] + bb1[f];
      a = a > 0.f ? a : 0.f;
#pragma unroll
      for (int h = 0; h < NH; ++h) acc[h] += a * w2[f * NH + h];
    }
#pragma unroll
    for (int h = 0; h < NH; ++h)
      phiA[(((size_t)l * NB + b) * NH + h) * QP + qp] = acc[h];
  }
  if (blockIdx.x < 128) {                                 // Wt transpose
    const int mat = blockIdx.x >> 3;                      // 16 matrices
    const int l = mat >> 2, wsel = mat & 3;
    const float* W = (wsel == 0 ? Wq : wsel == 1 ? Wk : wsel == 2 ? Wv : Wo) + l * DD * DD;
    const int j0 = (blockIdx.x & 7) * 32;
    short* outw = Wt + (size_t)mat * DD * DD;
    const int jj = t & 31, kk8 = t >> 5;
    for (int k0 = 0; k0 < DD; k0 += 32) {
      __syncthreads();
#pragma unroll
      for (int s = 0; s < 4; ++s) {
        const int kl = s * 8 + kk8;
        Ts[kl][jj] = W[(k0 + kl) * DD + j0 + jj];
      }
      __syncthreads();
#pragma unroll
      for (int s = 0; s < 4; ++s) {
        const int jl = (t >> 5) + s * 8;
        const int kl = t & 31;
        outw[(size_t)(j0 + jl) * DD + k0 + kl] = f2b(Ts[kl][jl]);
      }
    }
  }
}

// ---------------------------------------------------------------- fused qkv-proj + bias + attention
// One block per (b,h) (XCD swizzle), 512 threads = 8 waves.
// Phase A: q/k/v = BN(h) @ W-slices (MFMA; q,k computed transposed for packed scatter).
// Phase B: S = Q'K'^T with Q'=[q*scale, z], K'=[k, phi.z]; softmax; PV.
__global__ __launch_bounds__(512, 2) void k_fat(const float* __restrict__ hsrc,
                                                const short* __restrict__ WtL,   // layer base (4 mats)
                                                const float* __restrict__ bnstat,
                                                const float* __restrict__ gamma,
                                                const float* __restrict__ beta,
                                                const float* __restrict__ bq_l,
                                                const float* __restrict__ bk_l,
                                                const float* __restrict__ bv_l,
                                                const short* __restrict__ zbf,
                                                const float* __restrict__ phiAll,
                                                short* __restrict__ obf, int l) {
  // LDS map (159232 B total):
  //  [0, 98304)        Ks: K'[256 rows][384B pitch] -- phase A overlays Hs(64KB)+Ws(24KB) here
  //  [98304, 114688)   Vt: V^T[32][512B]
  //  [114688, 155648)  Pw: 8 waves x 5120B (qtmp 2560 + PV double-buffer)
  //  [155648, 156672)  rs_l (256 f32)
  //  [156672, 157184)  ph2 (128 f32)
  //  [157184, 159232)  bnsc/bnsh (256+256 f32)
  __shared__ __align__(16) char SM[159232];
  char* Ks = SM;
  char* Hs = SM;                      // phase A alias
  char* Ws = SM + 65536;              // phase A alias
  char* Vt = SM + 98304;
  char* Pw = SM + 114688;
  float* rs_l = (float*)(SM + 155648);
  float* ph2  = (float*)(SM + 156672);
  float* bnsc = (float*)(SM + 157184);
  float* bnsh = bnsc + 256;

  const int t = threadIdx.x;
  const int bh = (blockIdx.x & 7) * 32 + (blockIdx.x >> 3);   // XCD swizzle
  const int b = bh >> 3, hh = bh & 7;
  const int bnode = b * 256;

  bn_coeffs(bnstat, gamma, beta, bnsc, bnsh, t);
  if (t < 128)
    ph2[t] = phiAll[(((size_t)l * NB + b) * NH + hh) * QP + (t >> 1)];

  const int lane = t & 63, w = t >> 6;
  const int fr = lane & 15, fq = lane >> 4;

  // ---------------- phase A: qkv projection (wave w owns nodes w*32..w*32+32)
  // pf[n][m]: q/k TRANSPOSED (D row = kcol = fq*4+rr, D col = node = fr); n: q0 q1 k0 k1
  // po[m][n2]: v normal (D row = node = fq*4+rr, D col = vcol = fr)
  f32x4 pf[4][2] = {};
  f32x4 po[2][2] = {};
  for (int kb = 0; kb < 2; ++kb) {
    __syncthreads();
    // stage Hs: 256 rows x 128 cols bf16 (BN applied), pitch 256B, swizzled
#pragma unroll
    for (int p = 0; p < 8; ++p) {
      const int c = p * 512 + t;
      const int r = c >> 4, ch = c & 15;
      const int col0 = kb * 128 + ch * 8;
      const float* src = hsrc + (size_t)(bnode + r) * 256 + col0;
      const float4 v0 = *(const float4*)src;
      const float4 v1 = *(const float4*)(src + 4);
      short8v o;
      o[0] = f2b(v0.x * bnsc[col0 + 0] + bnsh[col0 + 0]);
      o[1] = f2b(v0.y * bnsc[col0 + 1] + bnsh[col0 + 1]);
      o[2] = f2b(v0.z * bnsc[col0 + 2] + bnsh[col0 + 2]);
      o[3] = f2b(v0.w * bnsc[col0 + 3] + bnsh[col0 + 3]);
      o[4] = f2b(v1.x * bnsc[col0 + 4] + bnsh[col0 + 4]);
      o[5] = f2b(v1.y * bnsc[col0 + 5] + bnsh[col0 + 5]);
      o[6] = f2b(v1.z * bnsc[col0 + 6] + bnsh[col0 + 6]);
      o[7] = f2b(v1.w * bnsc[col0 + 7] + bnsh[col0 + 7]);
      *(short8v*)(Hs + r * 256 + ((ch ^ (r & 7)) << 4)) = o;
    }
    // stage Ws: 96 rows (q/k/v slices for head hh) x 128 k, pitch 256B, swizzled
#pragma unroll
    for (int p = 0; p < 3; ++p) {
      const int c = p * 512 + t;
      const int r = c >> 4, ch = c & 15;
      const int mat = r >> 5, jj = r & 31;
      *(short8v*)(Ws + r * 256 + ((ch ^ (r & 7)) << 4)) =
          *(const short8v*)(WtL + ((size_t)mat * 256 + hh * 32 + jj) * 256 + kb * 128 + ch * 8);
    }
    __syncthreads();
#pragma unroll
    for (int ks = 0; ks < 4; ++ks) {
      short8v hfrag[2], wfrag[6];
#pragma unroll
      for (int m = 0; m < 2; ++m) {
        const int rA = w * 32 + m * 16 + fr;
        hfrag[m] = *(const short8v*)(Hs + rA * 256 + (((ks * 4 + fq) ^ (rA & 7)) << 4));
      }
#pragma unroll
      for (int n = 0; n < 6; ++n) {
        const int rB = n * 16 + fr;
        wfrag[n] = *(const short8v*)(Ws + rB * 256 + (((ks * 4 + fq) ^ (rB & 7)) << 4));
      }
#pragma unroll
      for (int n = 0; n < 4; ++n)
#pragma unroll
        for (int m = 0; m < 2; ++m)
          pf[n][m] = __builtin_amdgcn_mfma_f32_16x16x32_bf16(wfrag[n], hfrag[m], pf[n][m], 0, 0, 0);
#pragma unroll
      for (int m = 0; m < 2; ++m)
#pragma unroll
        for (int n2 = 0; n2 < 2; ++n2)
          po[m][n2] = __builtin_amdgcn_mfma_f32_16x16x32_bf16(hfrag[m], wfrag[4 + n2], po[m][n2], 0, 0, 0);
    }
  }
  __syncthreads();   // Hs/Ws dead; safe to overlay Ks

  // ---------------- phase A epilogue: packed short4 scatters
  char* qtmp = Pw + w * 5120;   // 32 rows x 80B
  {
    const float* bqp = bq_l + hh * 32;
    const float* bkp = bk_l + hh * 32;
    const float* bvp = bv_l + hh * 32;
    // q (transposed acc): lane col = node = fr; rows = kcol = n*16 + fq*4 + rr
#pragma unroll
    for (int n = 0; n < 2; ++n) {
      const int kcol0 = n * 16 + fq * 4;
#pragma unroll
      for (int m = 0; m < 2; ++m) {
        const int nodel = m * 16 + fr;
        short4 pk;
        pk.x = f2b((pf[n][m][0] + bqp[kcol0 + 0]) * QSCALE);
        pk.y = f2b((pf[n][m][1] + bqp[kcol0 + 1]) * QSCALE);
        pk.z = f2b((pf[n][m][2] + bqp[kcol0 + 2]) * QSCALE);
        pk.w = f2b((pf[n][m][3] + bqp[kcol0 + 3]) * QSCALE);
        *(short4*)(qtmp + nodel * 80 + kcol0 * 2) = pk;
      }
    }
    // k (transposed acc) -> Ks cols 0..31
#pragma unroll
    for (int n = 0; n < 2; ++n) {
      const int kcol0 = n * 16 + fq * 4;
#pragma unroll
      for (int m = 0; m < 2; ++m) {
        const int node = w * 32 + m * 16 + fr;
        short4 pk;
        pk.x = f2b(pf[2 + n][m][0] + bkp[kcol0 + 0]);
        pk.y = f2b(pf[2 + n][m][1] + bkp[kcol0 + 1]);
        pk.z = f2b(pf[2 + n][m][2] + bkp[kcol0 + 2]);
        pk.w = f2b(pf[2 + n][m][3] + bkp[kcol0 + 3]);
        *(short4*)(Ks + node * 384 + (((kcol0 >> 3) ^ (node & 7)) << 4) + (kcol0 & 7) * 2) = pk;
      }
    }
    // v (normal acc): lane col = vcol = fr; rows = node = w*32 + m*16 + fq*4 + rr
#pragma unroll
    for (int m = 0; m < 2; ++m) {
      const int node0 = w * 32 + m * 16 + fq * 4;
#pragma unroll
      for (int n2 = 0; n2 < 2; ++n2) {
        const int vcol = n2 * 16 + fr;
        const float bvv = bvp[vcol];
        short4 pk;
        pk.x = f2b(po[m][n2][0] + bvv);
        pk.y = f2b(po[m][n2][1] + bvv);
        pk.z = f2b(po[m][n2][2] + bvv);
        pk.w = f2b(po[m][n2][3] + bvv);
        *(short4*)(Vt + vcol * 512 + (((node0 >> 3) ^ (vcol & 7)) << 4) + (node0 & 7) * 2) = pk;
      }
    }
  }
  // ---------------- phase B staging: phi.z -> Ks cols 32..159
  {
    const int r = t >> 1, half = t & 1;
    const short* zrow = zbf + (size_t)(bnode + r) * 128 + half * 64;
#pragma unroll
    for (int cc = 0; cc < 8; ++cc) {
      const short8v zv = *(const short8v*)(zrow + cc * 8);
      const int zc = half * 64 + cc * 8;
      short8v o;
#pragma unroll
      for (int e = 0; e < 8; ++e)
        o[e] = f2b(b2f((unsigned short)zv[e]) * ph2[zc + e]);
      const int c = 4 + half * 8 + cc;
      *(short8v*)(Ks + r * 384 + ((c ^ (r & 7)) << 4)) = o;
    }
  }
  __syncthreads();

  const int i0w = w * 32;
  // Q' fragments: ks0 = q (from qtmp), ks1..4 = plain z (bf16 direct)
  short8v Qf[2][5];
#pragma unroll
  for (int s = 0; s < 2; ++s) {
    Qf[s][0] = *(const short8v*)(qtmp + (s * 16 + fr) * 80 + fq * 16);
    const short* zr = zbf + (size_t)(bnode + i0w + s * 16 + fr) * 128;
#pragma unroll
    for (int ks = 1; ks < 5; ++ks)
      Qf[s][ks] = *(const short8v*)(zr + (ks - 1) * 32 + fq * 8);
  }

  // S^T = K' Q'^T : acc[s][jt] lane holds S[q = i0w+s*16+fr][j = jt*16+fq*4+rr]
  f32x4 acc[2][16] = {};
  __builtin_amdgcn_s_setprio(1);
#pragma unroll
  for (int ks = 0; ks < 5; ++ks) {
#pragma unroll
    for (int jt = 0; jt < 16; ++jt) {
      const int row = jt * 16 + fr;
      const short8v a = *(const short8v*)(Ks + row * 384 + (((ks * 4 + fq) ^ (row & 7)) << 4));
      acc[0][jt] = __builtin_amdgcn_mfma_f32_16x16x32_bf16(a, Qf[0][ks], acc[0][jt], 0, 0, 0);
      acc[1][jt] = __builtin_amdgcn_mfma_f32_16x16x32_bf16(a, Qf[1][ks], acc[1][jt], 0, 0, 0);
    }
  }
  __builtin_amdgcn_s_setprio(0);

  float rsv0, rsv1;
#pragma unroll
  for (int s = 0; s < 2; ++s) {
    float m = -1e30f;
#pragma unroll
    for (int jt = 0; jt < 16; ++jt)
#pragma unroll
      for (int rr = 0; rr < 4; ++rr) m = fmaxf(m, acc[s][jt][rr]);
    m = fmaxf(m, __shfl_xor(m, 16));
    m = fmaxf(m, __shfl_xor(m, 32));
    float sm = 0.f;
#pragma unroll
    for (int jt = 0; jt < 16; ++jt)
#pragma unroll
      for (int rr = 0; rr < 4; ++rr) {
        const float e = __expf(acc[s][jt][rr] - m);
        acc[s][jt][rr] = e;
        sm += e;
      }
    sm += __shfl_xor(sm, 16);
    sm += __shfl_xor(sm, 32);
    const float r = 1.0f / sm;
    if (s == 0) rsv0 = r; else rsv1 = r;
  }
  if (fq == 0) rs_l[w * 32 + fr] = rsv0;
  if (fq == 1) rs_l[w * 32 + 16 + fr] = rsv1;

  // PV: per 32-j step, round-trip P through double-buffered per-wave LDS (reuses qtmp area)
  f32x4 oac[2][2] = {};
  char* pw0 = Pw + w * 5120;
#pragma unroll
  for (int ks = 0; ks < 8; ++ks) {
    char* pw = pw0 + (ks & 1) * 2560;
#pragma unroll
    for (int s = 0; s < 2; ++s)
#pragma unroll
      for (int j2 = 0; j2 < 2; ++j2) {
        const int jt = ks * 2 + j2;
        short4 pk;
        pk.x = f2b(acc[s][jt][0]); pk.y = f2b(acc[s][jt][1]);
        pk.z = f2b(acc[s][jt][2]); pk.w = f2b(acc[s][jt][3]);
        *(short4*)(pw + (s * 16 + fr) * 80 + j2 * 32 + fq * 8) = pk;
      }
    asm volatile("s_waitcnt lgkmcnt(0)" ::: "memory");
    __builtin_amdgcn_sched_barrier(0);
    const short8v pa0 = *(const short8v*)(pw + fr * 80 + fq * 16);
    const short8v pa1 = *(const short8v*)(pw + (16 + fr) * 80 + fq * 16);
    const int sw = (((ks * 4 + fq) ^ (fr & 7)) << 4);
    const short8v vb0 = *(const short8v*)(Vt + fr * 512 + sw);
    const short8v vb1 = *(const short8v*)(Vt + (16 + fr) * 512 + sw);
    oac[0][0] = __builtin_amdgcn_mfma_f32_16x16x32_bf16(pa0, vb0, oac[0][0], 0, 0, 0);
    oac[0][1] = __builtin_amdgcn_mfma_f32_16x16x32_bf16(pa0, vb1, oac[0][1], 0, 0, 0);
    oac[1][0] = __builtin_amdgcn_mfma_f32_16x16x32_bf16(pa1, vb0, oac[1][0], 0, 0, 0);
    oac[1][1] = __builtin_amdgcn_mfma_f32_16x16x32_bf16(pa1, vb1, oac[1][1], 0, 0, 0);
  }

#pragma unroll
  for (int s = 0; s < 2; ++s)
#pragma unroll
    for (int rr = 0; rr < 4; ++rr) {
      const float rs = rs_l[w * 32 + s * 16 + fq * 4 + rr];
      const int node = bnode + i0w + s * 16 + fq * 4 + rr;
#pragma unroll
      for (int nt = 0; nt < 2; ++nt)
        obf[(size_t)node * 256 + hh * 32 + nt * 16 + fr] = f2b(oac[s][nt][rr] * rs);
    }
}

// ---------------------------------------------------------------- fused O-proj + residual(BN) + stats
// grid (128, 2), 512 threads = 8 waves (2x4), each wave a 32x32 sub-tile of the 64x128 tile.
__global__ __launch_bounds__(512) void k_projo(const short* __restrict__ Abf,
                                               const short* __restrict__ WtO,
                                               const float* __restrict__ bo,
                                               const float* __restrict__ hin,
                                               float* __restrict__ hout,
                                               const float* __restrict__ bnstat,
                                               const float* __restrict__ gamma,
                                               const float* __restrict__ beta,
                                               float* __restrict__ bna) {
  __shared__ __align__(16) short As[64 * 128];
  __shared__ __align__(16) short Bs[128 * 128];
  __shared__ float sred[2][128][2];
  __shared__ float bnsc[256], bnsh[256];
  const int t = threadIdx.x;
  const int m0 = blockIdx.x * 64;
  const int c0 = blockIdx.y * 128;
  const int lane = t & 63, w = t >> 6;
  const int wr = w >> 2, wc = w & 3;       // 2 x 4 wave grid
  const int fr = lane & 15, fq = lane >> 4;

  bn_coeffs(bnstat, gamma, beta, bnsc, bnsh, t);

  f32x4 acc[2][2] = {};
  for (int kb = 0; kb < 2; ++kb) {
    __syncthreads();
#pragma unroll
    for (int p = 0; p < 2; ++p) {          // As: 64 rows x 16 chunks = 1024
      const int c = p * 512 + t;
      const int r = c >> 4, ch = c & 15;
      const int sw = ((ch ^ (r & 7)) << 4);
      *(short8v*)((char*)As + r * 256 + sw) =
          *(const short8v*)(Abf + (size_t)(m0 + r) * 256 + kb * 128 + ch * 8);
    }
#pragma unroll
    for (int p = 0; p < 4; ++p) {          // Bs: 128 rows x 16 chunks = 2048
      const int c = p * 512 + t;
      const int r = c >> 4, ch = c & 15;
      const int sw = ((ch ^ (r & 7)) << 4);
      *(short8v*)((char*)Bs + r * 256 + sw) =
          *(const short8v*)(WtO + (size_t)(c0 + r) * 256 + kb * 128 + ch * 8);
    }
    __syncthreads();
#pragma unroll
    for (int ks = 0; ks < 4; ++ks) {
      short8v a[2], bfrag[2];
#pragma unroll
      for (int m = 0; m < 2; ++m) {
        const int rA = wr * 32 + m * 16 + fr;
        a[m] = *(const short8v*)((const char*)As + rA * 256 + (((ks * 4 + fq) ^ (rA & 7)) << 4));
      }
#pragma unroll
      for (int n = 0; n < 2; ++n) {
        const int rB = wc * 32 + n * 16 + fr;
        bfrag[n] = *(const short8v*)((const char*)Bs + rB * 256 + (((ks * 4 + fq) ^ (rB & 7)) << 4));
      }
#pragma unroll
      for (int m = 0; m < 2; ++m)
#pragma unroll
        for (int n = 0; n < 2; ++n)
          acc[m][n] = __builtin_amdgcn_mfma_f32_16x16x32_bf16(a[m], bfrag[n], acc[m][n], 0, 0, 0);
    }
  }
#pragma unroll
  for (int n = 0; n < 2; ++n) {
    const int colLocal = wc * 32 + n * 16 + fr;
    const int col = c0 + colLocal;
    const float bv = bo[col];
    const float sc = bnsc[col], sh = bnsh[col];
    float s = 0.f, ss = 0.f;
#pragma unroll
    for (int m = 0; m < 2; ++m)
#pragma unroll
      for (int rr = 0; rr < 4; ++rr) {
        const int row = m0 + wr * 32 + m * 16 + fq * 4 + rr;
        const size_t idx = (size_t)row * 256 + col;
        const float v = acc[m][n][rr] + bv + (hin[idx] * sc + sh);
        hout[idx] = v;
        s += v;
        ss += v * v;
      }
    s += __shfl_xor(s, 16); s += __shfl_xor(s, 32);
    ss += __shfl_xor(ss, 16); ss += __shfl_xor(ss, 32);
    if (fq == 0) {
      sred[wr][colLocal][0] = s;
      sred[wr][colLocal][1] = ss;
    }
  }
  __syncthreads();
  if (t < 128) {
    const float s = sred[0][t][0] + sred[1][t][0];
    const float ss = sred[0][t][1] + sred[1][t][1];
    atomicAdd(&bna[c0 + t], s);
    atomicAdd(&bna[256 + c0 + t], ss);
  }
}

// ---------------------------------------------------------------- BN apply (final layer -> out), float4
__global__ __launch_bounds__(256) void k_bn_apply(const float* __restrict__ h,
                                                  const float* __restrict__ accum,
                                                  const float* __restrict__ gamma,
                                                  const float* __restrict__ beta,
                                                  float* __restrict__ outp, int l) {
  const int i4 = blockIdx.x * 256 + threadIdx.x;          // over HD2/4
  const int c0 = (i4 << 2) & 255;
  const float4 v = ((const float4*)h)[i4];
  float vv[4] = {v.x, v.y, v.z, v.w};
  float o[4];
#pragma unroll
  for (int e = 0; e < 4; ++e) {
    const int col = c0 + e;
    const float mean = accum[col] * (1.0f / NT);
    const float var = accum[DD + col] * (1.0f / NT) - mean * mean;
    o[e] = (vv[e] - mean) * rsqrtf(var + 1e-5f) * gamma[l * DD + col] + beta[l * DD + col];
  }
  ((float4*)outp)[i4] = make_float4(o[0], o[1], o[2], o[3]);
}

// ================================================================ host
extern "C" void kernel_launch(void* const* d_in, const int* in_sizes, int n_in,
                              void* d_out, int out_size, void* d_ws, size_t ws_size,
                              hipStream_t stream) {
  (void)in_sizes; (void)n_in; (void)out_size; (void)ws_size;
  const float* x    = (const float*)d_in[0];
  const float* z    = (const float*)d_in[1];
  const float* Lam  = (const float*)d_in[2];
  const float* Wq   = (const float*)d_in[4];
  const float* Wk   = (const float*)d_in[5];
  const float* Wv   = (const float*)d_in[6];
  const float* Wo   = (const float*)d_in[7];
  const float* bq   = (const float*)d_in[8];
  const float* bk   = (const float*)d_in[9];
  const float* bv   = (const float*)d_in[10];
  const float* bo   = (const float*)d_in[11];
  const float* pW1  = (const float*)d_in[12];
  const float* pb1  = (const float*)d_in[13];
  const float* pW2  = (const float*)d_in[14];
  const float* pb2  = (const float*)d_in[15];
  const float* gam  = (const float*)d_in[16];
  const float* bet  = (const float*)d_in[17];
  float* out = (float*)d_out;

  float* h    = (float*)d_ws;                 // 8 MB fp32 running h (pre-BN)
  short* obf  = (short*)(h + HD2);            // attn out bf16 (4 MB)
  short* zbf  = obf + HD2;                    // 2 MB bf16 z
  short* Wt   = zbf + NT * 128;               // 2 MB (16 mats x 256x256 bf16)
  float* phiA = (float*)(Wt + 16 * DD * DD);  // 32 KB
  float* bna  = phiA + 4 * NB * NH * QP;      // 4 layers x 512

  k_setup<<<1024, 256, 0, stream>>>(z, out + HD2, zbf, bna, Lam, pW1, pb1, pW2, pb2,
                                    phiA, Wq, Wk, Wv, Wo, Wt);
  for (int l = 0; l < 4; ++l) {
    const float* bnprev = l ? bna + (l - 1) * 512 : nullptr;
    const float* gprev  = gam + (l ? (l - 1) * DD : 0);
    const float* bprev  = bet + (l ? (l - 1) * DD : 0);
    const float* hsrc   = l ? h : x;
    k_fat<<<256, 512, 0, stream>>>(hsrc, Wt + (size_t)l * 4 * DD * DD,
                                   bnprev, gprev, bprev,
                                   bq + l * DD, bk + l * DD, bv + l * DD,
                                   zbf, phiA, obf, l);
    k_projo<<<dim3(128, 2), 512, 0, stream>>>(obf, Wt + (size_t)(l * 4 + 3) * DD * DD,
                                              bo + l * DD, hsrc, h,
                                              bnprev, gprev, bprev, bna + l * 512);
  }
  k_bn_apply<<<2048, 256, 0, stream>>>(h, bna + 3 * 512, gam, bet, out, 3);
}